// Round 6
// baseline (211.672 us; speedup 1.0000x reference)
//
#include <hip/hip_runtime.h>

// TimeConvX: truncated temporal spectral conv (FNO-style), T=16, M=3 modes, C=8.
// out[t,b,c] = v[t,b,c] + irfft( einsum('bim,iom->bom', rfft(v)[..,:3], w) )
// R6: software pipeline across 4 columns per thread (2 register buffers A/B,
// 16 dwordx4 each). While column k computes (~2400cy), column k+1's 16 loads
// are in flight -> continuous memory duty instead of load/compute bursts.
// Grid 768 blocks; per-slice block window 16KB contiguous. XCD-bijective
// swizzle. Exact fp32 residual. launch_bounds(256,2) so A+B+state fits.

#define TT 16
#define CC 8
#define MM 3
#define T4STRIDE (131072 * 3 * 8 / 4)  // float4 stride between t slices = 786432
#define NBLK4 768                      // (2*393216)/256/4
#define NXCD 8
#define BPX (NBLK4 / NXCD)             // 96

typedef float f4 __attribute__((ext_vector_type(4)));

static constexpr float C1[TT] = {
     1.0f,  0.9238795325f,  0.7071067812f,  0.3826834324f,
     0.0f, -0.3826834324f, -0.7071067812f, -0.9238795325f,
    -1.0f, -0.9238795325f, -0.7071067812f, -0.3826834324f,
     0.0f,  0.3826834324f,  0.7071067812f,  0.9238795325f };
static constexpr float S1[TT] = {
     0.0f,  0.3826834324f,  0.7071067812f,  0.9238795325f,
     1.0f,  0.9238795325f,  0.7071067812f,  0.3826834324f,
     0.0f, -0.3826834324f, -0.7071067812f, -0.9238795325f,
    -1.0f, -0.9238795325f, -0.7071067812f, -0.3826834324f };
static constexpr float C2[TT] = {
     1.0f,  0.7071067812f,  0.0f, -0.7071067812f,
    -1.0f, -0.7071067812f,  0.0f,  0.7071067812f,
     1.0f,  0.7071067812f,  0.0f, -0.7071067812f,
    -1.0f, -0.7071067812f,  0.0f,  0.7071067812f };
static constexpr float S2[TT] = {
     0.0f,  0.7071067812f,  1.0f,  0.7071067812f,
     0.0f, -0.7071067812f, -1.0f, -0.7071067812f,
     0.0f,  0.7071067812f,  1.0f,  0.7071067812f,
     0.0f, -0.7071067812f, -1.0f, -0.7071067812f };

__device__ __forceinline__ void load_col(const f4* __restrict__ vp, f4 (&a)[TT]) {
    #pragma unroll
    for (int t = 0; t < TT; ++t)
        a[t] = vp[(size_t)t * T4STRIDE];
}

__device__ __forceinline__ void proc_col(const f4 (&a)[TT],
                                         f4* __restrict__ op,
                                         const int half,
                                         const float* __restrict__ s_wr,
                                         const float* __restrict__ s_wi)
{
    // ---- forward: X[j][m], m=0,1,2 (m=0 imag = 0) ----
    float Xr0[4], Xr1[4], Xi1[4], Xr2[4], Xi2[4];
    #pragma unroll
    for (int j = 0; j < 4; ++j) { Xr0[j]=0.f; Xr1[j]=0.f; Xi1[j]=0.f; Xr2[j]=0.f; Xi2[j]=0.f; }
    #pragma unroll
    for (int t = 0; t < TT; ++t) {
        const float c1 = C1[t], s1 = S1[t], c2 = C2[t], s2 = S2[t];
        #pragma unroll
        for (int j = 0; j < 4; ++j) {
            const float xv = a[t][j];
            Xr0[j] += xv;
            Xr1[j] += xv * c1;
            Xi1[j] -= xv * s1;
            Xr2[j] += xv * c2;
            Xi2[j] -= xv * s2;
        }
    }

    // ---- exchange partner lane's spectra (other 4 channels) ----
    float Yr0[4], Yr1[4], Yi1[4], Yr2[4], Yi2[4];
    #pragma unroll
    for (int j = 0; j < 4; ++j) {
        Yr0[j] = __shfl_xor(Xr0[j], 1, 64);
        Yr1[j] = __shfl_xor(Xr1[j], 1, 64);
        Yi1[j] = __shfl_xor(Xi1[j], 1, 64);
        Yr2[j] = __shfl_xor(Xr2[j], 1, 64);
        Yi2[j] = __shfl_xor(Xi2[j], 1, 64);
    }
    float ALr0[4], ALr1[4], ALi1[4], ALr2[4], ALi2[4];
    float AHr0[4], AHr1[4], AHi1[4], AHr2[4], AHi2[4];
    #pragma unroll
    for (int j = 0; j < 4; ++j) {
        ALr0[j] = half ? Yr0[j] : Xr0[j];  AHr0[j] = half ? Xr0[j] : Yr0[j];
        ALr1[j] = half ? Yr1[j] : Xr1[j];  AHr1[j] = half ? Xr1[j] : Yr1[j];
        ALi1[j] = half ? Yi1[j] : Xi1[j];  AHi1[j] = half ? Xi1[j] : Yi1[j];
        ALr2[j] = half ? Yr2[j] : Xr2[j];  AHr2[j] = half ? Xr2[j] : Yr2[j];
        ALi2[j] = half ? Yi2[j] : Xi2[j];  AHi2[j] = half ? Xi2[j] : Yi2[j];
    }

    // ---- channel mix for own 4 output channels o = half*4 + j ----
    const int obase = half * 4;
    float Fr0[4], Fr1[4], Fi1[4], Fr2[4], Fi2[4];
    #pragma unroll
    for (int j = 0; j < 4; ++j) {
        const int o3 = (obase + j) * MM;
        float fr0 = 0.f, fr1 = 0.f, fi1 = 0.f, fr2 = 0.f, fi2 = 0.f;
        #pragma unroll
        for (int i = 0; i < 4; ++i) {       // input channels 0-3
            const int w3 = i * CC * MM + o3;
            const float w0 = s_wr[w3 + 0];
            const float w1r = s_wr[w3 + 1], w1i = s_wi[w3 + 1];
            const float w2r = s_wr[w3 + 2], w2i = s_wi[w3 + 2];
            fr0 += ALr0[i] * w0;
            fr1 += ALr1[i] * w1r - ALi1[i] * w1i;
            fi1 += ALr1[i] * w1i + ALi1[i] * w1r;
            fr2 += ALr2[i] * w2r - ALi2[i] * w2i;
            fi2 += ALr2[i] * w2i + ALi2[i] * w2r;
        }
        #pragma unroll
        for (int i = 0; i < 4; ++i) {       // input channels 4-7
            const int w3 = (i + 4) * CC * MM + o3;
            const float w0 = s_wr[w3 + 0];
            const float w1r = s_wr[w3 + 1], w1i = s_wi[w3 + 1];
            const float w2r = s_wr[w3 + 2], w2i = s_wi[w3 + 2];
            fr0 += AHr0[i] * w0;
            fr1 += AHr1[i] * w1r - AHi1[i] * w1i;
            fi1 += AHr1[i] * w1i + AHi1[i] * w1r;
            fr2 += AHr2[i] * w2r - AHi2[i] * w2i;
            fi2 += AHr2[i] * w2i + AHi2[i] * w2r;
        }
        Fr0[j] = fr0 * 0.0625f;   // 1/16 (DC); imag of DC dropped by irfft
        Fr1[j] = fr1 * 0.125f;    // 2/16 (modes 1,2)
        Fi1[j] = fi1 * 0.125f;
        Fr2[j] = fr2 * 0.125f;
        Fi2[j] = fi2 * 0.125f;
    }

    // ---- inverse + exact fp32 residual + store ----
    #pragma unroll
    for (int t = 0; t < TT; ++t) {
        const float c1 = C1[t], s1 = S1[t], c2 = C2[t], s2 = S2[t];
        f4 r;
        #pragma unroll
        for (int j = 0; j < 4; ++j) {
            float yy = Fr0[j];
            yy += c1 * Fr1[j];
            yy -= s1 * Fi1[j];
            yy += c2 * Fr2[j];
            yy -= s2 * Fi2[j];
            r[j] = a[t][j] + yy;
        }
        op[(size_t)t * T4STRIDE] = r;
    }
}

__global__ __launch_bounds__(256, 2) void timeconvx_kernel(
    const f4* __restrict__ v4,
    const float* __restrict__ wr,
    const float* __restrict__ wi,
    f4* __restrict__ out4)
{
    __shared__ float s_wr[CC * CC * MM];
    __shared__ float s_wi[CC * CC * MM];
    const int tid = threadIdx.x;
    if (tid < CC * CC * MM) {
        s_wr[tid] = wr[tid];
        s_wi[tid] = wi[tid];
    }

    // XCD-bijective swizzle over 768 blocks (96 per XCD, contiguous).
    const int bid = blockIdx.x;
    const int lb = (bid & (NXCD - 1)) * BPX + (bid >> 3);
    const int half = tid & 1;               // 0: ch 0-3, 1: ch 4-7 (parity of g)

    const int g0 = (lb * 4 + 0) * 256 + tid;
    const int g1 = (lb * 4 + 1) * 256 + tid;
    const int g2 = (lb * 4 + 2) * 256 + tid;
    const int g3 = (lb * 4 + 3) * 256 + tid;

    f4 A[TT], B[TT];

    load_col(v4 + g0, A);
    __builtin_amdgcn_sched_barrier(0);      // A(g0) loads all issued
    load_col(v4 + g1, B);
    __builtin_amdgcn_sched_barrier(0);      // B(g1) loads all issued (32 in flight)

    __syncthreads();                        // weights visible (overlaps load latency)

    proc_col(A, out4 + g0, half, s_wr, s_wi);   // B(g1) in flight underneath
    load_col(v4 + g2, A);                        // reuse A regs
    __builtin_amdgcn_sched_barrier(0);
    proc_col(B, out4 + g1, half, s_wr, s_wi);   // A(g2) in flight underneath
    load_col(v4 + g3, B);
    __builtin_amdgcn_sched_barrier(0);
    proc_col(A, out4 + g2, half, s_wr, s_wi);   // B(g3) in flight underneath
    proc_col(B, out4 + g3, half, s_wr, s_wi);
}

extern "C" void kernel_launch(void* const* d_in, const int* in_sizes, int n_in,
                              void* d_out, int out_size, void* d_ws, size_t ws_size,
                              hipStream_t stream) {
    const f4* v4     = (const f4*)d_in[0];
    const float* wr  = (const float*)d_in[1];
    const float* wi  = (const float*)d_in[2];
    f4* out4 = (f4*)d_out;

    timeconvx_kernel<<<NBLK4, 256, 0, stream>>>(v4, wr, wi, out4);
}

// Round 7
// 99.603 us; speedup vs baseline: 2.1252x; 2.1252x over previous
//
#include <hip/hip_runtime.h>

// TimeConvX: truncated temporal spectral conv (FNO-style), T=16, M=3 modes, C=8.
// out[t,b,c] = v[t,b,c] + irfft( einsum('bim,iom->bom', rfft(v)[..,:3], w) )
// R7: LDS double-buffered streaming pipeline (T3/T4 mechanics).
//  - 768 blocks x 256 threads; each block processes 4 consecutive 256-elem
//    "columns"; 1 block/CU (128 KB LDS) -> breadth-first balanced.
//  - Each wave owns private 2x16KB LDS; global_load_lds (width 16) stages
//    column k+1 (16 instrs, no VGPR dests) while column k computes from LDS.
//  - Counted waits: s_waitcnt vmcnt(32) keeps next-col loads + prev-col stores
//    in flight across column boundaries (never drains to 0 mid-loop).
//  - Raw s_barrier + sched_barrier(0) fence buffer reuse (WAR) without the
//    __syncthreads() vmcnt(0) drain (m201-verified behavior).

#define TT 16
#define CC 8
#define MM 3
#define T4STRIDE (131072 * 3 * 8 / 4)  // f4 stride between t slices = 786432
#define NBLOCKS 768
#define COLS_PB 4                      // 768*4 = 3072 columns = 786432 threads-equiv
#define NXCD 8
#define BPX (NBLOCKS / NXCD)           // 96

typedef float f4 __attribute__((ext_vector_type(4)));
typedef const __attribute__((address_space(1))) unsigned int* gas_ptr;
typedef __attribute__((address_space(3))) unsigned int* las_ptr;

static constexpr float C1[TT] = {
     1.0f,  0.9238795325f,  0.7071067812f,  0.3826834324f,
     0.0f, -0.3826834324f, -0.7071067812f, -0.9238795325f,
    -1.0f, -0.9238795325f, -0.7071067812f, -0.3826834324f,
     0.0f,  0.3826834324f,  0.7071067812f,  0.9238795325f };
static constexpr float S1[TT] = {
     0.0f,  0.3826834324f,  0.7071067812f,  0.9238795325f,
     1.0f,  0.9238795325f,  0.7071067812f,  0.3826834324f,
     0.0f, -0.3826834324f, -0.7071067812f, -0.9238795325f,
    -1.0f, -0.9238795325f, -0.7071067812f, -0.3826834324f };
static constexpr float C2[TT] = {
     1.0f,  0.7071067812f,  0.0f, -0.7071067812f,
    -1.0f, -0.7071067812f,  0.0f,  0.7071067812f,
     1.0f,  0.7071067812f,  0.0f, -0.7071067812f,
    -1.0f, -0.7071067812f,  0.0f,  0.7071067812f };
static constexpr float S2[TT] = {
     0.0f,  0.7071067812f,  1.0f,  0.7071067812f,
     0.0f, -0.7071067812f, -1.0f, -0.7071067812f,
     0.0f,  0.7071067812f,  1.0f,  0.7071067812f,
     0.0f, -0.7071067812f, -1.0f, -0.7071067812f };

// Stage one column's 16 t-slices into this wave's LDS region.
// LDS dest is wave-uniform base + lane*16 (HW); global src is per-lane.
__device__ __forceinline__ void issue_col(const f4* __restrict__ gsrc, char* ldsbase) {
    #pragma unroll
    for (int t = 0; t < TT; ++t) {
        __builtin_amdgcn_global_load_lds(
            (gas_ptr)(const void*)(gsrc + (size_t)t * T4STRIDE),
            (las_ptr)(void*)(ldsbase + t * 1024),
            16, 0, 0);
    }
}

__device__ __forceinline__ void compute_col(
    const f4* __restrict__ xl,      // LDS, index t*64 + lane
    const int lane, const int half,
    const float* __restrict__ swr, const float* __restrict__ swi,
    f4* __restrict__ op)            // out4 + col*256 + tid
{
    // ---- forward: X[j][m], m=0,1,2 (m=0 imag = 0) ----
    float Xr0[4], Xr1[4], Xi1[4], Xr2[4], Xi2[4];
    #pragma unroll
    for (int j = 0; j < 4; ++j) { Xr0[j]=0.f; Xr1[j]=0.f; Xi1[j]=0.f; Xr2[j]=0.f; Xi2[j]=0.f; }
    #pragma unroll
    for (int t = 0; t < TT; ++t) {
        const f4 a = xl[t * 64 + lane];
        const float c1 = C1[t], s1 = S1[t], c2 = C2[t], s2 = S2[t];
        #pragma unroll
        for (int j = 0; j < 4; ++j) {
            const float xv = a[j];
            Xr0[j] += xv;
            Xr1[j] += xv * c1;
            Xi1[j] -= xv * s1;
            Xr2[j] += xv * c2;
            Xi2[j] -= xv * s2;
        }
    }

    // ---- exchange partner lane's spectra (other 4 channels) ----
    float Yr0[4], Yr1[4], Yi1[4], Yr2[4], Yi2[4];
    #pragma unroll
    for (int j = 0; j < 4; ++j) {
        Yr0[j] = __shfl_xor(Xr0[j], 1, 64);
        Yr1[j] = __shfl_xor(Xr1[j], 1, 64);
        Yi1[j] = __shfl_xor(Xi1[j], 1, 64);
        Yr2[j] = __shfl_xor(Xr2[j], 1, 64);
        Yi2[j] = __shfl_xor(Xi2[j], 1, 64);
    }
    float ALr0[4], ALr1[4], ALi1[4], ALr2[4], ALi2[4];
    float AHr0[4], AHr1[4], AHi1[4], AHr2[4], AHi2[4];
    #pragma unroll
    for (int j = 0; j < 4; ++j) {
        ALr0[j] = half ? Yr0[j] : Xr0[j];  AHr0[j] = half ? Xr0[j] : Yr0[j];
        ALr1[j] = half ? Yr1[j] : Xr1[j];  AHr1[j] = half ? Xr1[j] : Yr1[j];
        ALi1[j] = half ? Yi1[j] : Xi1[j];  AHi1[j] = half ? Xi1[j] : Yi1[j];
        ALr2[j] = half ? Yr2[j] : Xr2[j];  AHr2[j] = half ? Xr2[j] : Yr2[j];
        ALi2[j] = half ? Yi2[j] : Xi2[j];  AHi2[j] = half ? Xi2[j] : Yi2[j];
    }

    // ---- channel mix for own 4 output channels o = half*4 + j ----
    const int obase = half * 4;
    float Fr0[4], Fr1[4], Fi1[4], Fr2[4], Fi2[4];
    #pragma unroll
    for (int j = 0; j < 4; ++j) {
        const int o3 = (obase + j) * MM;
        float fr0 = 0.f, fr1 = 0.f, fi1 = 0.f, fr2 = 0.f, fi2 = 0.f;
        #pragma unroll
        for (int i = 0; i < 4; ++i) {       // input channels 0-3
            const int w3 = i * CC * MM + o3;
            const float w0 = swr[w3 + 0];
            const float w1r = swr[w3 + 1], w1i = swi[w3 + 1];
            const float w2r = swr[w3 + 2], w2i = swi[w3 + 2];
            fr0 += ALr0[i] * w0;
            fr1 += ALr1[i] * w1r - ALi1[i] * w1i;
            fi1 += ALr1[i] * w1i + ALi1[i] * w1r;
            fr2 += ALr2[i] * w2r - ALi2[i] * w2i;
            fi2 += ALr2[i] * w2i + ALi2[i] * w2r;
        }
        #pragma unroll
        for (int i = 0; i < 4; ++i) {       // input channels 4-7
            const int w3 = (i + 4) * CC * MM + o3;
            const float w0 = swr[w3 + 0];
            const float w1r = swr[w3 + 1], w1i = swi[w3 + 1];
            const float w2r = swr[w3 + 2], w2i = swi[w3 + 2];
            fr0 += AHr0[i] * w0;
            fr1 += AHr1[i] * w1r - AHi1[i] * w1i;
            fi1 += AHr1[i] * w1i + AHi1[i] * w1r;
            fr2 += AHr2[i] * w2r - AHi2[i] * w2i;
            fi2 += AHr2[i] * w2i + AHi2[i] * w2r;
        }
        Fr0[j] = fr0 * 0.0625f;   // 1/16 (DC); imag of DC dropped by irfft
        Fr1[j] = fr1 * 0.125f;    // 2/16 (modes 1,2)
        Fi1[j] = fi1 * 0.125f;
        Fr2[j] = fr2 * 0.125f;
        Fi2[j] = fi2 * 0.125f;
    }

    // ---- inverse + exact fp32 residual (re-read LDS) + store ----
    #pragma unroll
    for (int t = 0; t < TT; ++t) {
        const f4 a = xl[t * 64 + lane];
        const float c1 = C1[t], s1 = S1[t], c2 = C2[t], s2 = S2[t];
        f4 r;
        #pragma unroll
        for (int j = 0; j < 4; ++j) {
            float yy = Fr0[j];
            yy += c1 * Fr1[j];
            yy -= s1 * Fi1[j];
            yy += c2 * Fr2[j];
            yy -= s2 * Fi2[j];
            r[j] = a[j] + yy;
        }
        op[(size_t)t * T4STRIDE] = r;
    }
}

#define FENCE() do { __builtin_amdgcn_sched_barrier(0); } while (0)
#define COLBAR() do { __builtin_amdgcn_sched_barrier(0); __builtin_amdgcn_s_barrier(); } while (0)

__global__ __launch_bounds__(256) void timeconvx_kernel(
    const f4* __restrict__ v4,
    const float* __restrict__ wr,
    const float* __restrict__ wi,
    f4* __restrict__ out4)
{
    __shared__ __align__(16) char smem[131072];      // 2 bufs x 4 waves x 16 KB
    __shared__ float s_wr[CC * CC * MM];
    __shared__ float s_wi[CC * CC * MM];
    const int tid = threadIdx.x;
    if (tid < CC * CC * MM) {
        s_wr[tid] = wr[tid];
        s_wi[tid] = wi[tid];
    }
    __syncthreads();   // drains only the 2 weight loads (before any staging)

    // XCD-bijective block swizzle (768 = 8 * 96).
    const int bid = blockIdx.x;
    const int lb  = (bid & (NXCD - 1)) * BPX + (bid >> 3);
    const int w    = tid >> 6;
    const int lane = tid & 63;
    const int half = tid & 1;                 // column base is even -> parity = tid&1

    const size_t base0 = (size_t)(lb * COLS_PB) * 256 + tid;
    char* bA = smem + w * 16384;              // even columns
    char* bB = smem + 65536 + w * 16384;      // odd columns
    const f4* rA = (const f4*)bA;
    const f4* rB = (const f4*)bB;

    // ---- prologue: stage col0 -> A, col1 -> B ----
    issue_col(v4 + base0, bA);
    FENCE();
    issue_col(v4 + base0 + 256, bB);
    FENCE();

    // ---- col 0 ----
    asm volatile("s_waitcnt vmcnt(16)" ::: "memory");   // col0 loads done; col1 in flight
    FENCE();
    compute_col(rA, lane, half, s_wr, s_wi, out4 + base0);
    COLBAR();

    // ---- col 1 (stage col2 -> A) ----
    issue_col(v4 + base0 + 2 * 256, bA);
    FENCE();
    asm volatile("s_waitcnt vmcnt(32)" ::: "memory");   // col1 done; col2 loads + col0 stores in flight
    FENCE();
    compute_col(rB, lane, half, s_wr, s_wi, out4 + base0 + 256);
    COLBAR();

    // ---- col 2 (stage col3 -> B) ----
    issue_col(v4 + base0 + 3 * 256, bB);
    FENCE();
    asm volatile("s_waitcnt vmcnt(32)" ::: "memory");   // col2 done; col3 loads + col1 stores in flight
    FENCE();
    compute_col(rA, lane, half, s_wr, s_wi, out4 + base0 + 2 * 256);
    COLBAR();

    // ---- col 3 (tail) ----
    asm volatile("s_waitcnt vmcnt(16)" ::: "memory");   // col3 done; col2 stores in flight
    FENCE();
    compute_col(rB, lane, half, s_wr, s_wi, out4 + base0 + 3 * 256);
}

extern "C" void kernel_launch(void* const* d_in, const int* in_sizes, int n_in,
                              void* d_out, int out_size, void* d_ws, size_t ws_size,
                              hipStream_t stream) {
    const f4* v4     = (const f4*)d_in[0];
    const float* wr  = (const float*)d_in[1];
    const float* wi  = (const float*)d_in[2];
    f4* out4 = (f4*)d_out;

    timeconvx_kernel<<<NBLOCKS, 256, 0, stream>>>(v4, wr, wi, out4);
}

// Round 8
// 72.669 us; speedup vs baseline: 2.9128x; 1.3706x over previous
//
#include <hip/hip_runtime.h>

// TimeConvX: truncated temporal spectral conv (FNO-style), T=16, M=3 modes, C=8.
// out[t,b,c] = v[t,b,c] + irfft( einsum('bim,iom->bom', rfft(v)[..,:3], w) )
// R8 = R7 (LDS dbuf + counted vmcnt, wave-private staging) plus:
//  - NO per-column s_barrier: LDS regions are wave-private; waves free-run.
//  - Non-temporal stores: out bypasses LLC allocate -> v (201MB) stays
//    L3-resident across replays (R7 already showed FETCH at 50% of ideal).
//  - 512 blocks x 6 columns (2 dispatch rounds, prologue paid 2x not 3x).

#define TT 16
#define CC 8
#define MM 3
#define T4STRIDE (131072 * 3 * 8 / 4)  // f4 stride between t slices = 786432
#define NBLOCKS 512
#define COLS_PB 6                      // 512*6*256 = 786432 columns-threads
#define NXCD 8
#define BPX (NBLOCKS / NXCD)           // 64

typedef float f4 __attribute__((ext_vector_type(4)));
typedef const __attribute__((address_space(1))) unsigned int* gas_ptr;
typedef __attribute__((address_space(3))) unsigned int* las_ptr;

static constexpr float C1[TT] = {
     1.0f,  0.9238795325f,  0.7071067812f,  0.3826834324f,
     0.0f, -0.3826834324f, -0.7071067812f, -0.9238795325f,
    -1.0f, -0.9238795325f, -0.7071067812f, -0.3826834324f,
     0.0f,  0.3826834324f,  0.7071067812f,  0.9238795325f };
static constexpr float S1[TT] = {
     0.0f,  0.3826834324f,  0.7071067812f,  0.9238795325f,
     1.0f,  0.9238795325f,  0.7071067812f,  0.3826834324f,
     0.0f, -0.3826834324f, -0.7071067812f, -0.9238795325f,
    -1.0f, -0.9238795325f, -0.7071067812f, -0.3826834324f };
static constexpr float C2[TT] = {
     1.0f,  0.7071067812f,  0.0f, -0.7071067812f,
    -1.0f, -0.7071067812f,  0.0f,  0.7071067812f,
     1.0f,  0.7071067812f,  0.0f, -0.7071067812f,
    -1.0f, -0.7071067812f,  0.0f,  0.7071067812f };
static constexpr float S2[TT] = {
     0.0f,  0.7071067812f,  1.0f,  0.7071067812f,
     0.0f, -0.7071067812f, -1.0f, -0.7071067812f,
     0.0f,  0.7071067812f,  1.0f,  0.7071067812f,
     0.0f, -0.7071067812f, -1.0f, -0.7071067812f };

// Stage one column's 16 t-slices into this wave's private LDS region.
__device__ __forceinline__ void issue_col(const f4* __restrict__ gsrc, char* ldsbase) {
    #pragma unroll
    for (int t = 0; t < TT; ++t) {
        __builtin_amdgcn_global_load_lds(
            (gas_ptr)(const void*)(gsrc + (size_t)t * T4STRIDE),
            (las_ptr)(void*)(ldsbase + t * 1024),
            16, 0, 0);
    }
}

__device__ __forceinline__ void compute_col(
    const f4* __restrict__ xl,      // LDS, index t*64 + lane
    const int lane, const int half,
    const float* __restrict__ swr, const float* __restrict__ swi,
    f4* __restrict__ op)
{
    // ---- forward: X[j][m], m=0,1,2 (m=0 imag = 0) ----
    float Xr0[4], Xr1[4], Xi1[4], Xr2[4], Xi2[4];
    #pragma unroll
    for (int j = 0; j < 4; ++j) { Xr0[j]=0.f; Xr1[j]=0.f; Xi1[j]=0.f; Xr2[j]=0.f; Xi2[j]=0.f; }
    #pragma unroll
    for (int t = 0; t < TT; ++t) {
        const f4 a = xl[t * 64 + lane];
        const float c1 = C1[t], s1 = S1[t], c2 = C2[t], s2 = S2[t];
        #pragma unroll
        for (int j = 0; j < 4; ++j) {
            const float xv = a[j];
            Xr0[j] += xv;
            Xr1[j] += xv * c1;
            Xi1[j] -= xv * s1;
            Xr2[j] += xv * c2;
            Xi2[j] -= xv * s2;
        }
    }

    // ---- exchange partner lane's spectra (other 4 channels) ----
    float Yr0[4], Yr1[4], Yi1[4], Yr2[4], Yi2[4];
    #pragma unroll
    for (int j = 0; j < 4; ++j) {
        Yr0[j] = __shfl_xor(Xr0[j], 1, 64);
        Yr1[j] = __shfl_xor(Xr1[j], 1, 64);
        Yi1[j] = __shfl_xor(Xi1[j], 1, 64);
        Yr2[j] = __shfl_xor(Xr2[j], 1, 64);
        Yi2[j] = __shfl_xor(Xi2[j], 1, 64);
    }
    float ALr0[4], ALr1[4], ALi1[4], ALr2[4], ALi2[4];
    float AHr0[4], AHr1[4], AHi1[4], AHr2[4], AHi2[4];
    #pragma unroll
    for (int j = 0; j < 4; ++j) {
        ALr0[j] = half ? Yr0[j] : Xr0[j];  AHr0[j] = half ? Xr0[j] : Yr0[j];
        ALr1[j] = half ? Yr1[j] : Xr1[j];  AHr1[j] = half ? Xr1[j] : Yr1[j];
        ALi1[j] = half ? Yi1[j] : Xi1[j];  AHi1[j] = half ? Xi1[j] : Yi1[j];
        ALr2[j] = half ? Yr2[j] : Xr2[j];  AHr2[j] = half ? Xr2[j] : Yr2[j];
        ALi2[j] = half ? Yi2[j] : Xi2[j];  AHi2[j] = half ? Xi2[j] : Yi2[j];
    }

    // ---- channel mix for own 4 output channels o = half*4 + j ----
    const int obase = half * 4;
    float Fr0[4], Fr1[4], Fi1[4], Fr2[4], Fi2[4];
    #pragma unroll
    for (int j = 0; j < 4; ++j) {
        const int o3 = (obase + j) * MM;
        float fr0 = 0.f, fr1 = 0.f, fi1 = 0.f, fr2 = 0.f, fi2 = 0.f;
        #pragma unroll
        for (int i = 0; i < 4; ++i) {       // input channels 0-3
            const int w3 = i * CC * MM + o3;
            const float w0 = swr[w3 + 0];
            const float w1r = swr[w3 + 1], w1i = swi[w3 + 1];
            const float w2r = swr[w3 + 2], w2i = swi[w3 + 2];
            fr0 += ALr0[i] * w0;
            fr1 += ALr1[i] * w1r - ALi1[i] * w1i;
            fi1 += ALr1[i] * w1i + ALi1[i] * w1r;
            fr2 += ALr2[i] * w2r - ALi2[i] * w2i;
            fi2 += ALr2[i] * w2i + ALi2[i] * w2r;
        }
        #pragma unroll
        for (int i = 0; i < 4; ++i) {       // input channels 4-7
            const int w3 = (i + 4) * CC * MM + o3;
            const float w0 = swr[w3 + 0];
            const float w1r = swr[w3 + 1], w1i = swi[w3 + 1];
            const float w2r = swr[w3 + 2], w2i = swi[w3 + 2];
            fr0 += AHr0[i] * w0;
            fr1 += AHr1[i] * w1r - AHi1[i] * w1i;
            fi1 += AHr1[i] * w1i + AHi1[i] * w1r;
            fr2 += AHr2[i] * w2r - AHi2[i] * w2i;
            fi2 += AHr2[i] * w2i + AHi2[i] * w2r;
        }
        Fr0[j] = fr0 * 0.0625f;   // 1/16 (DC); imag of DC dropped by irfft
        Fr1[j] = fr1 * 0.125f;    // 2/16 (modes 1,2)
        Fi1[j] = fi1 * 0.125f;
        Fr2[j] = fr2 * 0.125f;
        Fi2[j] = fi2 * 0.125f;
    }

    // ---- inverse + exact fp32 residual (re-read LDS) + NT store ----
    #pragma unroll
    for (int t = 0; t < TT; ++t) {
        const f4 a = xl[t * 64 + lane];
        const float c1 = C1[t], s1 = S1[t], c2 = C2[t], s2 = S2[t];
        f4 r;
        #pragma unroll
        for (int j = 0; j < 4; ++j) {
            float yy = Fr0[j];
            yy += c1 * Fr1[j];
            yy -= s1 * Fi1[j];
            yy += c2 * Fr2[j];
            yy -= s2 * Fi2[j];
            r[j] = a[j] + yy;
        }
        __builtin_nontemporal_store(r, op + (size_t)t * T4STRIDE);
    }
}

#define FENCE() __builtin_amdgcn_sched_barrier(0)

__global__ __launch_bounds__(256) void timeconvx_kernel(
    const f4* __restrict__ v4,
    const float* __restrict__ wr,
    const float* __restrict__ wi,
    f4* __restrict__ out4)
{
    __shared__ __align__(16) char smem[131072];      // 2 bufs x 4 waves x 16 KB
    __shared__ float s_wr[CC * CC * MM];
    __shared__ float s_wi[CC * CC * MM];
    const int tid = threadIdx.x;
    if (tid < CC * CC * MM) {
        s_wr[tid] = wr[tid];
        s_wi[tid] = wi[tid];
    }
    __syncthreads();   // weights visible; only barrier in the kernel

    // XCD-bijective block swizzle (512 = 8 * 64).
    const int bid = blockIdx.x;
    const int lb  = (bid & (NXCD - 1)) * BPX + (bid >> 3);
    const int w    = tid >> 6;
    const int lane = tid & 63;
    const int half = tid & 1;

    const size_t base0 = (size_t)(lb * COLS_PB) * 256 + tid;
    char* bA = smem + w * 16384;              // even columns
    char* bB = smem + 65536 + w * 16384;      // odd columns
    const f4* rA = (const f4*)bA;
    const f4* rB = (const f4*)bB;

    // ---- prologue: stage col0 -> A, col1 -> B ----
    issue_col(v4 + base0, bA);
    FENCE();
    issue_col(v4 + base0 + 256, bB);
    FENCE();

    // schedule per column c (wave-private, no block barrier):
    //   [issue (c+1)L for c>=1]  wait  compute(c)+stores
    // waits: c0 -> vmcnt(16); middle -> vmcnt(32) (keeps next loads + prev
    // stores in flight); last -> vmcnt(16).

    // ---- col 0 ----
    asm volatile("s_waitcnt vmcnt(16)" ::: "memory");
    FENCE();
    compute_col(rA, lane, half, s_wr, s_wi, out4 + base0);
    FENCE();

    // ---- col 1 (stage col2 -> A) ----
    issue_col(v4 + base0 + 2 * 256, bA);
    FENCE();
    asm volatile("s_waitcnt vmcnt(32)" ::: "memory");
    FENCE();
    compute_col(rB, lane, half, s_wr, s_wi, out4 + base0 + 256);
    FENCE();

    // ---- col 2 (stage col3 -> B) ----
    issue_col(v4 + base0 + 3 * 256, bB);
    FENCE();
    asm volatile("s_waitcnt vmcnt(32)" ::: "memory");
    FENCE();
    compute_col(rA, lane, half, s_wr, s_wi, out4 + base0 + 2 * 256);
    FENCE();

    // ---- col 3 (stage col4 -> A) ----
    issue_col(v4 + base0 + 4 * 256, bA);
    FENCE();
    asm volatile("s_waitcnt vmcnt(32)" ::: "memory");
    FENCE();
    compute_col(rB, lane, half, s_wr, s_wi, out4 + base0 + 3 * 256);
    FENCE();

    // ---- col 4 (stage col5 -> B) ----
    issue_col(v4 + base0 + 5 * 256, bB);
    FENCE();
    asm volatile("s_waitcnt vmcnt(32)" ::: "memory");
    FENCE();
    compute_col(rA, lane, half, s_wr, s_wi, out4 + base0 + 4 * 256);
    FENCE();

    // ---- col 5 (tail) ----
    asm volatile("s_waitcnt vmcnt(16)" ::: "memory");
    FENCE();
    compute_col(rB, lane, half, s_wr, s_wi, out4 + base0 + 5 * 256);
}

extern "C" void kernel_launch(void* const* d_in, const int* in_sizes, int n_in,
                              void* d_out, int out_size, void* d_ws, size_t ws_size,
                              hipStream_t stream) {
    const f4* v4     = (const f4*)d_in[0];
    const float* wr  = (const float*)d_in[1];
    const float* wi  = (const float*)d_in[2];
    f4* out4 = (f4*)d_out;

    timeconvx_kernel<<<NBLOCKS, 256, 0, stream>>>(v4, wr, wi, out4);
}

// Round 9
// 71.793 us; speedup vs baseline: 2.9484x; 1.0122x over previous
//
#include <hip/hip_runtime.h>

// TimeConvX: truncated temporal spectral conv (FNO-style), T=16, M=3 modes, C=8.
// out[t,b,c] = v[t,b,c] + irfft( einsum('bim,iom->bom', rfft(v)[..,:3], w) )
// R9 = R8 (wave-private LDS dbuf + global_load_lds + counted vmcnt + NT stores)
// with single-round scheduling: 256 blocks (exactly 1/CU, persistent) x 12
// columns. Prologue paid once; no inter-round drain. Main loop not unrolled
// (2 columns/iter, static A/B buffer naming) to keep I-cache small.
// vmcnt ledger (stage always precedes compute's stores, in-order retire):
//   head wait(16): [c0 L][c1 L] -> drains c0 L.
//   1st-half wait(32): [c(2m+1)L][c(2m)S][c(2m+2)L] -> drains c(2m+1) L.
//   2nd-half wait(32): [c(2m)S][c(2m+2)L][c(2m+1)S][c(2m+3)L] -> drains
//     c(2m)S + c(2m+2)L.
//   tail wait(16): [c11 L][c10 S] -> drains c11 L.

#define TT 16
#define CC 8
#define MM 3
#define T4STRIDE (131072 * 3 * 8 / 4)  // f4 stride between t slices = 786432
#define NBLOCKS 256
#define COLS_PB 12                     // 256*12*256 = 786432 column-threads
#define NXCD 8
#define BPX (NBLOCKS / NXCD)           // 32

typedef float f4 __attribute__((ext_vector_type(4)));
typedef const __attribute__((address_space(1))) unsigned int* gas_ptr;
typedef __attribute__((address_space(3))) unsigned int* las_ptr;

static constexpr float C1[TT] = {
     1.0f,  0.9238795325f,  0.7071067812f,  0.3826834324f,
     0.0f, -0.3826834324f, -0.7071067812f, -0.9238795325f,
    -1.0f, -0.9238795325f, -0.7071067812f, -0.3826834324f,
     0.0f,  0.3826834324f,  0.7071067812f,  0.9238795325f };
static constexpr float S1[TT] = {
     0.0f,  0.3826834324f,  0.7071067812f,  0.9238795325f,
     1.0f,  0.9238795325f,  0.7071067812f,  0.3826834324f,
     0.0f, -0.3826834324f, -0.7071067812f, -0.9238795325f,
    -1.0f, -0.9238795325f, -0.7071067812f, -0.3826834324f };
static constexpr float C2[TT] = {
     1.0f,  0.7071067812f,  0.0f, -0.7071067812f,
    -1.0f, -0.7071067812f,  0.0f,  0.7071067812f,
     1.0f,  0.7071067812f,  0.0f, -0.7071067812f,
    -1.0f, -0.7071067812f,  0.0f,  0.7071067812f };
static constexpr float S2[TT] = {
     0.0f,  0.7071067812f,  1.0f,  0.7071067812f,
     0.0f, -0.7071067812f, -1.0f, -0.7071067812f,
     0.0f,  0.7071067812f,  1.0f,  0.7071067812f,
     0.0f, -0.7071067812f, -1.0f, -0.7071067812f };

// Stage one column's 16 t-slices into this wave's private LDS region.
__device__ __forceinline__ void issue_col(const f4* __restrict__ gsrc, char* ldsbase) {
    #pragma unroll
    for (int t = 0; t < TT; ++t) {
        __builtin_amdgcn_global_load_lds(
            (gas_ptr)(const void*)(gsrc + (size_t)t * T4STRIDE),
            (las_ptr)(void*)(ldsbase + t * 1024),
            16, 0, 0);
    }
}

__device__ __forceinline__ void compute_col(
    const f4* __restrict__ xl,      // LDS, index t*64 + lane
    const int lane, const int half,
    const float* __restrict__ swr, const float* __restrict__ swi,
    f4* __restrict__ op)
{
    // ---- forward: X[j][m], m=0,1,2 (m=0 imag = 0) ----
    float Xr0[4], Xr1[4], Xi1[4], Xr2[4], Xi2[4];
    #pragma unroll
    for (int j = 0; j < 4; ++j) { Xr0[j]=0.f; Xr1[j]=0.f; Xi1[j]=0.f; Xr2[j]=0.f; Xi2[j]=0.f; }
    #pragma unroll
    for (int t = 0; t < TT; ++t) {
        const f4 a = xl[t * 64 + lane];
        const float c1 = C1[t], s1 = S1[t], c2 = C2[t], s2 = S2[t];
        #pragma unroll
        for (int j = 0; j < 4; ++j) {
            const float xv = a[j];
            Xr0[j] += xv;
            Xr1[j] += xv * c1;
            Xi1[j] -= xv * s1;
            Xr2[j] += xv * c2;
            Xi2[j] -= xv * s2;
        }
    }

    // ---- exchange partner lane's spectra (other 4 channels) ----
    float Yr0[4], Yr1[4], Yi1[4], Yr2[4], Yi2[4];
    #pragma unroll
    for (int j = 0; j < 4; ++j) {
        Yr0[j] = __shfl_xor(Xr0[j], 1, 64);
        Yr1[j] = __shfl_xor(Xr1[j], 1, 64);
        Yi1[j] = __shfl_xor(Xi1[j], 1, 64);
        Yr2[j] = __shfl_xor(Xr2[j], 1, 64);
        Yi2[j] = __shfl_xor(Xi2[j], 1, 64);
    }
    float ALr0[4], ALr1[4], ALi1[4], ALr2[4], ALi2[4];
    float AHr0[4], AHr1[4], AHi1[4], AHr2[4], AHi2[4];
    #pragma unroll
    for (int j = 0; j < 4; ++j) {
        ALr0[j] = half ? Yr0[j] : Xr0[j];  AHr0[j] = half ? Xr0[j] : Yr0[j];
        ALr1[j] = half ? Yr1[j] : Xr1[j];  AHr1[j] = half ? Xr1[j] : Yr1[j];
        ALi1[j] = half ? Yi1[j] : Xi1[j];  AHi1[j] = half ? Xi1[j] : Yi1[j];
        ALr2[j] = half ? Yr2[j] : Xr2[j];  AHr2[j] = half ? Xr2[j] : Yr2[j];
        ALi2[j] = half ? Yi2[j] : Xi2[j];  AHi2[j] = half ? Xi2[j] : Yi2[j];
    }

    // ---- channel mix for own 4 output channels o = half*4 + j ----
    const int obase = half * 4;
    float Fr0[4], Fr1[4], Fi1[4], Fr2[4], Fi2[4];
    #pragma unroll
    for (int j = 0; j < 4; ++j) {
        const int o3 = (obase + j) * MM;
        float fr0 = 0.f, fr1 = 0.f, fi1 = 0.f, fr2 = 0.f, fi2 = 0.f;
        #pragma unroll
        for (int i = 0; i < 4; ++i) {       // input channels 0-3
            const int w3 = i * CC * MM + o3;
            const float w0 = swr[w3 + 0];
            const float w1r = swr[w3 + 1], w1i = swi[w3 + 1];
            const float w2r = swr[w3 + 2], w2i = swi[w3 + 2];
            fr0 += ALr0[i] * w0;
            fr1 += ALr1[i] * w1r - ALi1[i] * w1i;
            fi1 += ALr1[i] * w1i + ALi1[i] * w1r;
            fr2 += ALr2[i] * w2r - ALi2[i] * w2i;
            fi2 += ALr2[i] * w2i + ALi2[i] * w2r;
        }
        #pragma unroll
        for (int i = 0; i < 4; ++i) {       // input channels 4-7
            const int w3 = (i + 4) * CC * MM + o3;
            const float w0 = swr[w3 + 0];
            const float w1r = swr[w3 + 1], w1i = swi[w3 + 1];
            const float w2r = swr[w3 + 2], w2i = swi[w3 + 2];
            fr0 += AHr0[i] * w0;
            fr1 += AHr1[i] * w1r - AHi1[i] * w1i;
            fi1 += AHr1[i] * w1i + AHi1[i] * w1r;
            fr2 += AHr2[i] * w2r - AHi2[i] * w2i;
            fi2 += AHr2[i] * w2i + AHi2[i] * w2r;
        }
        Fr0[j] = fr0 * 0.0625f;   // 1/16 (DC); imag of DC dropped by irfft
        Fr1[j] = fr1 * 0.125f;    // 2/16 (modes 1,2)
        Fi1[j] = fi1 * 0.125f;
        Fr2[j] = fr2 * 0.125f;
        Fi2[j] = fi2 * 0.125f;
    }

    // ---- inverse + exact fp32 residual (re-read LDS) + NT store ----
    #pragma unroll
    for (int t = 0; t < TT; ++t) {
        const f4 a = xl[t * 64 + lane];
        const float c1 = C1[t], s1 = S1[t], c2 = C2[t], s2 = S2[t];
        f4 r;
        #pragma unroll
        for (int j = 0; j < 4; ++j) {
            float yy = Fr0[j];
            yy += c1 * Fr1[j];
            yy -= s1 * Fi1[j];
            yy += c2 * Fr2[j];
            yy -= s2 * Fi2[j];
            r[j] = a[j] + yy;
        }
        __builtin_nontemporal_store(r, op + (size_t)t * T4STRIDE);
    }
}

#define FENCE() __builtin_amdgcn_sched_barrier(0)
#define WAIT16() do { asm volatile("s_waitcnt vmcnt(16)" ::: "memory"); FENCE(); } while (0)
#define WAIT32() do { asm volatile("s_waitcnt vmcnt(32)" ::: "memory"); FENCE(); } while (0)

__global__ __launch_bounds__(256) void timeconvx_kernel(
    const f4* __restrict__ v4,
    const float* __restrict__ wr,
    const float* __restrict__ wi,
    f4* __restrict__ out4)
{
    __shared__ __align__(16) char smem[131072];      // 2 bufs x 4 waves x 16 KB
    __shared__ float s_wr[CC * CC * MM];
    __shared__ float s_wi[CC * CC * MM];
    const int tid = threadIdx.x;
    if (tid < CC * CC * MM) {
        s_wr[tid] = wr[tid];
        s_wi[tid] = wi[tid];
    }
    __syncthreads();   // weights visible; only block barrier in the kernel

    // XCD-bijective block swizzle (256 = 8 * 32).
    const int bid = blockIdx.x;
    const int lb  = (bid & (NXCD - 1)) * BPX + (bid >> 3);
    const int w    = tid >> 6;
    const int lane = tid & 63;
    const int half = tid & 1;

    const size_t base0 = (size_t)(lb * COLS_PB) * 256 + tid;
    char* bA = smem + w * 16384;              // even columns
    char* bB = smem + 65536 + w * 16384;      // odd columns
    const f4* rA = (const f4*)bA;
    const f4* rB = (const f4*)bB;

    // ---- prologue: stage col0 -> A, col1 -> B; compute col0 ----
    issue_col(v4 + base0, bA);
    FENCE();
    issue_col(v4 + base0 + 256, bB);
    FENCE();
    WAIT16();
    compute_col(rA, lane, half, s_wr, s_wi, out4 + base0);
    FENCE();

    // ---- main loop: 5 iters x 2 columns (static A/B naming, not unrolled) ----
    #pragma unroll 1
    for (int m = 0; m < 5; ++m) {
        const size_t c1o = base0 + (size_t)(2 * m + 1) * 256;
        const size_t c2o = base0 + (size_t)(2 * m + 2) * 256;
        const size_t c3o = base0 + (size_t)(2 * m + 3) * 256;

        issue_col(v4 + c2o, bA);          // stage even col -> A
        FENCE();
        WAIT32();                          // odd col's loads (B) done
        compute_col(rB, lane, half, s_wr, s_wi, out4 + c1o);
        FENCE();

        issue_col(v4 + c3o, bB);          // stage odd col -> B
        FENCE();
        WAIT32();                          // even col's loads (A) done
        compute_col(rA, lane, half, s_wr, s_wi, out4 + c2o);
        FENCE();
    }

    // ---- tail: col 11 (B) ----
    WAIT16();
    compute_col(rB, lane, half, s_wr, s_wi, out4 + base0 + 11 * 256);
}

extern "C" void kernel_launch(void* const* d_in, const int* in_sizes, int n_in,
                              void* d_out, int out_size, void* d_ws, size_t ws_size,
                              hipStream_t stream) {
    const f4* v4     = (const f4*)d_in[0];
    const float* wr  = (const float*)d_in[1];
    const float* wi  = (const float*)d_in[2];
    f4* out4 = (f4*)d_out;

    timeconvx_kernel<<<NBLOCKS, 256, 0, stream>>>(v4, wr, wi, out4);
}